// Round 12
// baseline (99.744 us; speedup 1.0000x reference)
//
#include <hip/hip_runtime.h>

// Chamfer distance: B=4, N=M=8192, D=3, fp32 -> scalar.
// MFMA formulation (layout verified R9, absmax 0): d2 = |q|^2+|t|^2-2q.t
// packed into K=16 of mfma_f32_32x32x16_bf16 via bf16 hi/lo splitting.
// R12: 4 col-tiles/iter. MFMA outputs reduced by compiler fminf (hazard-
// safe; inline asm reading MFMA dst skips hazard nops -> R10/R11 failures),
// then v_min3_f32 only on VALU-produced values. 12 VALU issues/MFMA ->
// matrix-bound (per-CU: 12.3K VALU cyc vs 16.5K matrix cyc).

#define B_ 4
#define N_ 8192
#define THREADS 512

typedef float f32x16 __attribute__((ext_vector_type(16)));
typedef short short8 __attribute__((ext_vector_type(8)));
typedef unsigned short ushort8 __attribute__((ext_vector_type(8)));

__device__ __forceinline__ float min3f(float a, float b, float c) {
  float d;
  asm("v_min3_f32 %0, %1, %2, %3" : "=v"(d) : "v"(a), "v"(b), "v"(c));
  return d;
}

__device__ __forceinline__ unsigned short f2bf(float x) {
  unsigned u = __float_as_uint(x);
  u = u + 0x7FFFu + ((u >> 16) & 1u);          // RNE
  return (unsigned short)(u >> 16);
}
__device__ __forceinline__ float bf2f(unsigned short h) {
  return __uint_as_float(((unsigned)h) << 16);
}

// Pack A-form (rows) and B-form (cols) for both directions.
// Apack: [0..32768) = pred (dir0 rows), [32768..) = gt (dir1 rows).
// Bpack: [0..32768) = gt   (dir0 cols), [32768..) = pred (dir1 cols).
__global__ __launch_bounds__(256) void chamfer_pack(
    const float* __restrict__ pred, const float* __restrict__ gt,
    unsigned short* __restrict__ Apack, unsigned short* __restrict__ Bpack,
    float* __restrict__ accws) {
  const int i = blockIdx.x * 256 + threadIdx.x;   // 0..65535
  if (i < 2) ((unsigned*)accws)[i] = 0u;          // zero sum + counter
  const int half = B_ * N_;
  const float* src = (i < half) ? pred : gt;
  const int k = (i < half) ? i : i - half;
  const float x = src[3 * k], y = src[3 * k + 1], z = src[3 * k + 2];
  const float q2 = fmaf(x, x, fmaf(y, y, z * z));

  const float ux = -2.f * x, uy = -2.f * y, uz = -2.f * z;
  const unsigned short uhx = f2bf(ux), uhy = f2bf(uy), uhz = f2bf(uz);
  const unsigned short ulx = f2bf(ux - bf2f(uhx));
  const unsigned short uly = f2bf(uy - bf2f(uhy));
  const unsigned short ulz = f2bf(uz - bf2f(uhz));
  const unsigned short thx = f2bf(x), thy = f2bf(y), thz = f2bf(z);
  const unsigned short tlx = f2bf(x - bf2f(thx));
  const unsigned short tly = f2bf(y - bf2f(thy));
  const unsigned short tlz = f2bf(z - bf2f(thz));
  const unsigned short q2h = f2bf(q2);
  const unsigned short q2l = f2bf(q2 - bf2f(q2h));
  const unsigned short one = 0x3F80u;

  const size_t aslot = (size_t)i;
  const size_t bslot = (size_t)((i < half) ? i + half : i - half);

  ushort8 alo = {uhx, uhy, uhz, uhx, uhy, uhz, ulx, uly};
  ushort8 ahi = {ulz, q2h, q2l, one, one, 0, 0, 0};
  ushort8 blo = {thx, thy, thz, tlx, tly, tlz, thx, thy};
  ushort8 bhi = {thz, one, one, q2h, q2l, 0, 0, 0};
  *(ushort8*)(Apack + aslot * 16) = alo;
  *(ushort8*)(Apack + aslot * 16 + 8) = ahi;
  *(ushort8*)(Bpack + bslot * 16) = blo;
  *(ushort8*)(Bpack + bslot * 16 + 8) = bhi;
}

// grid (128 panels, 8 dirb). 8 waves = 2 row-subtiles x 4 col-slices.
// Block owns 64 rows; sweeps 8192 cols. Per iter (per wave): 4 tiles at
// col offsets {0,128,256,384} -> 4 MFMAs; fminf pairs + min3 racc fold;
// advance 512 cols (8192 shorts), 16 iters.
__global__ __launch_bounds__(THREADS, 4) void chamfer_mfma(
    const unsigned short* __restrict__ Apack,
    const unsigned short* __restrict__ Bpack,
    float* __restrict__ rowmin) {
  __shared__ unsigned rowlds[64];
  const int tid = threadIdx.x;
  const int dirb = blockIdx.y;            // dir*4 + b
  const int panel = blockIdx.x;           // 64-row panel
  const int w = tid >> 6, l = tid & 63;
  const int wr = w >> 2, wc = w & 3;
  const int l31 = l & 31, lhi = l >> 5;

  if (tid < 64) rowlds[tid] = 0x7F7FFFFFu;
  __syncthreads();

  // A fragment (fixed per wave): row = panel*64 + wr*32 + l31, k-half by lhi.
  const int row = panel * 64 + wr * 32 + l31;
  const short8 afrag =
      *(const short8*)(Apack + ((size_t)dirb * N_ + row) * 16 + lhi * 8);

  // B fragment base: col = wc*32 + l31 (slot = 16 shorts).
  const unsigned short* bp =
      Bpack + ((size_t)dirb * N_ + wc * 32 + l31) * 16 + lhi * 8;

  const f32x16 zacc = {};
  float racc[16];
#pragma unroll
  for (int r = 0; r < 16; ++r) racc[r] = 3.4e38f;

  for (int it = 0; it < 16; ++it) {
    const unsigned short* p = bp + (size_t)it * 8192;   // 512 cols/iter
    const short8 b0 = *(const short8*)(p);
    const short8 b1 = *(const short8*)(p + 2048);       // +128 cols
    const short8 b2 = *(const short8*)(p + 4096);       // +256 cols
    const short8 b3 = *(const short8*)(p + 6144);       // +384 cols
    const f32x16 d0 =
        __builtin_amdgcn_mfma_f32_32x32x16_bf16(afrag, b0, zacc, 0, 0, 0);
    const f32x16 d1 =
        __builtin_amdgcn_mfma_f32_32x32x16_bf16(afrag, b1, zacc, 0, 0, 0);
    const f32x16 d2 =
        __builtin_amdgcn_mfma_f32_32x32x16_bf16(afrag, b2, zacc, 0, 0, 0);
    const f32x16 d3 =
        __builtin_amdgcn_mfma_f32_32x32x16_bf16(afrag, b3, zacc, 0, 0, 0);
#pragma unroll
    for (int r = 0; r < 16; ++r) {
      const float t01 = fminf(d0[r], d1[r]);   // compiler: MFMA hazards handled
      const float t23 = fminf(d2[r], d3[r]);
      racc[r] = min3f(racc[r], t01, t23);      // asm on VALU-produced values only
    }
  }

  // clamp, butterfly over 32 col-lanes
#pragma unroll
  for (int r = 0; r < 16; ++r) racc[r] = fmaxf(racc[r], 0.0f);
#pragma unroll
  for (int m = 1; m <= 16; m <<= 1)
#pragma unroll
    for (int r = 0; r < 16; ++r)
      racc[r] = fminf(racc[r], __shfl_xor(racc[r], m, 64));

  // lanes 0 / 32 hold 16-row mins for their half; combine across wc-waves
  if (l31 == 0) {
#pragma unroll
    for (int r = 0; r < 16; ++r) {
      const int lr = wr * 32 + (r & 3) + 8 * (r >> 2) + 4 * lhi;
      atomicMin(&rowlds[lr], __float_as_uint(racc[r]));
    }
  }
  __syncthreads();
  if (tid < 64)
    rowmin[(size_t)dirb * N_ + panel * 64 + tid] = __uint_as_float(rowlds[tid]);
}

// 65536 d2 mins -> sqrt -> sum -> scaled scalar (counter-trick final write).
__global__ __launch_bounds__(256) void chamfer_fin(
    const float* __restrict__ rowmin, float* __restrict__ accws,
    float* __restrict__ out) {
  const int t = blockIdx.x * 256 + threadIdx.x;   // 0..16383
  const float4 v = ((const float4*)rowmin)[t];
  float sum = sqrtf(fmaxf(v.x, 0.f)) + sqrtf(fmaxf(v.y, 0.f)) +
              sqrtf(fmaxf(v.z, 0.f)) + sqrtf(fmaxf(v.w, 0.f));
#pragma unroll
  for (int off = 32; off > 0; off >>= 1) sum += __shfl_down(sum, off, 64);
  __shared__ float ws4[4];
  const int lane = threadIdx.x & 63, wid = threadIdx.x >> 6;
  if (lane == 0) ws4[wid] = sum;
  __syncthreads();
  if (threadIdx.x == 0) {
    const float bs = (ws4[0] + ws4[1]) + (ws4[2] + ws4[3]);
    atomicAdd(&accws[0], bs);
    __threadfence();
    const unsigned old = atomicAdd(((unsigned*)accws) + 1, 1u);
    if (old == gridDim.x - 1) {
      __threadfence();
      const float tot = atomicAdd(&accws[0], 0.0f);
      out[0] = tot * (1.0f / 32768.0f);   // /(B*N) per direction, N==M
    }
  }
}

extern "C" void kernel_launch(void* const* d_in, const int* in_sizes, int n_in,
                              void* d_out, int out_size, void* d_ws, size_t ws_size,
                              hipStream_t stream) {
  const float* pred = (const float*)d_in[0];  // [B, N, 3]
  const float* gt   = (const float*)d_in[1];  // [B, M, 3]
  float* out = (float*)d_out;

  float* accws = (float*)d_ws;                                   // 2 words
  unsigned short* Apack = (unsigned short*)((char*)d_ws + 64);   // 2 MB
  unsigned short* Bpack = Apack + (size_t)2 * B_ * N_ * 16;      // 2 MB
  float* rowmin = (float*)(Bpack + (size_t)2 * B_ * N_ * 16);    // 256 KB

  chamfer_pack<<<256, 256, 0, stream>>>(pred, gt, Apack, Bpack, accws);
  chamfer_mfma<<<dim3(128, 8), THREADS, 0, stream>>>(Apack, Bpack, rowmin);
  chamfer_fin<<<64, 256, 0, stream>>>(rowmin, accws, out);
}

// Round 14
// 97.108 us; speedup vs baseline: 1.0271x; 1.0271x over previous
//
#include <hip/hip_runtime.h>

// Chamfer distance: B=4, N=M=8192, D=3, fp32 -> scalar.
// MFMA formulation (layout verified R9/R12, absmax 0): d2=|q|^2+|t|^2-2q.t
// packed into K=16 of mfma_f32_32x32x16_bf16 via bf16 hi/lo splitting.
// R14: R13 (double-buffered global_load_lds B-staging) with LDS cut to
// 32.25 KB (2 x 16 KB chunks of 512 cols) -- R13's 65.8 KB static LDS
// exceeded the 64 KB limit and likely killed the launch.

#define B_ 4
#define N_ 8192
#define THREADS 512
#define CHUNK_COLS 512
#define NCHUNK (N_ / CHUNK_COLS)     // 16

typedef float f32x16 __attribute__((ext_vector_type(16)));
typedef short short8 __attribute__((ext_vector_type(8)));
typedef unsigned short ushort8 __attribute__((ext_vector_type(8)));

__device__ __forceinline__ unsigned short f2bf(float x) {
  unsigned u = __float_as_uint(x);
  u = u + 0x7FFFu + ((u >> 16) & 1u);          // RNE
  return (unsigned short)(u >> 16);
}
__device__ __forceinline__ float bf2f(unsigned short h) {
  return __uint_as_float(((unsigned)h) << 16);
}

// Pack A-form (rows) and B-form (cols) for both directions.
// Apack: [0..32768) = pred (dir0 rows), [32768..) = gt (dir1 rows).
// Bpack: [0..32768) = gt   (dir0 cols), [32768..) = pred (dir1 cols).
__global__ __launch_bounds__(256) void chamfer_pack(
    const float* __restrict__ pred, const float* __restrict__ gt,
    unsigned short* __restrict__ Apack, unsigned short* __restrict__ Bpack,
    float* __restrict__ accws) {
  const int i = blockIdx.x * 256 + threadIdx.x;   // 0..65535
  if (i < 2) ((unsigned*)accws)[i] = 0u;          // zero sum + counter
  const int half = B_ * N_;
  const float* src = (i < half) ? pred : gt;
  const int k = (i < half) ? i : i - half;
  const float x = src[3 * k], y = src[3 * k + 1], z = src[3 * k + 2];
  const float q2 = fmaf(x, x, fmaf(y, y, z * z));

  const float ux = -2.f * x, uy = -2.f * y, uz = -2.f * z;
  const unsigned short uhx = f2bf(ux), uhy = f2bf(uy), uhz = f2bf(uz);
  const unsigned short ulx = f2bf(ux - bf2f(uhx));
  const unsigned short uly = f2bf(uy - bf2f(uhy));
  const unsigned short ulz = f2bf(uz - bf2f(uhz));
  const unsigned short thx = f2bf(x), thy = f2bf(y), thz = f2bf(z);
  const unsigned short tlx = f2bf(x - bf2f(thx));
  const unsigned short tly = f2bf(y - bf2f(thy));
  const unsigned short tlz = f2bf(z - bf2f(thz));
  const unsigned short q2h = f2bf(q2);
  const unsigned short q2l = f2bf(q2 - bf2f(q2h));
  const unsigned short one = 0x3F80u;

  const size_t aslot = (size_t)i;
  const size_t bslot = (size_t)((i < half) ? i + half : i - half);

  ushort8 alo = {uhx, uhy, uhz, uhx, uhy, uhz, ulx, uly};
  ushort8 ahi = {ulz, q2h, q2l, one, one, 0, 0, 0};
  ushort8 blo = {thx, thy, thz, tlx, tly, tlz, thx, thy};
  ushort8 bhi = {thz, one, one, q2h, q2l, 0, 0, 0};
  *(ushort8*)(Apack + aslot * 16) = alo;
  *(ushort8*)(Apack + aslot * 16 + 8) = ahi;
  *(ushort8*)(Bpack + bslot * 16) = blo;
  *(ushort8*)(Bpack + bslot * 16 + 8) = bhi;
}

// Stage this wave's 64-col slice of a chunk (2 KB) via global_load_lds.
// LDS dest is wave-uniform base (HW adds lane*16); global src is per-lane.
__device__ __forceinline__ void stage_chunk(
    const unsigned short* __restrict__ Bdir, int chunk,
    unsigned short* ldsbase, int w, int l) {
  const unsigned short* g =
      Bdir + (size_t)chunk * CHUNK_COLS * 16 + (size_t)(w * 64) * 16 + l * 8;
  unsigned short* d = ldsbase + (w * 64) * 16;
#pragma unroll
  for (int k = 0; k < 2; ++k) {
    __builtin_amdgcn_global_load_lds(
        (const __attribute__((address_space(1))) unsigned int*)(g + k * 512),
        (__attribute__((address_space(3))) unsigned int*)(d + k * 512),
        16, 0, 0);
  }
}

// grid (128 panels, 8 dirb), 512 threads = 8 waves. Block owns 64 rows
// (2 A-banks/wave); each wave sweeps its 64-col slice of each chunk.
__global__ __launch_bounds__(THREADS, 4) void chamfer_mfma(
    const unsigned short* __restrict__ Apack,
    const unsigned short* __restrict__ Bpack,
    float* __restrict__ rowmin) {
  __shared__ unsigned short buf[2][CHUNK_COLS * 16];   // 2 x 16 KB
  __shared__ unsigned rowlds[64];

  const int tid = threadIdx.x;
  const int dirb = blockIdx.y;            // dir*4 + b
  const int panel = blockIdx.x;           // 64-row panel
  const int w = tid >> 6, l = tid & 63;
  const int l31 = l & 31, lhi = l >> 5;

  if (tid < 64) rowlds[tid] = 0x7F7FFFFFu;

  // A fragments: rows panel*64 + l31 (bank0), +32 (bank1); k-half by lhi.
  const size_t abase = ((size_t)dirb * N_ + panel * 64) * 16;
  const short8 afrag0 = *(const short8*)(Apack + abase + (size_t)l31 * 16 + lhi * 8);
  const short8 afrag1 = *(const short8*)(Apack + abase + (size_t)(32 + l31) * 16 + lhi * 8);

  const unsigned short* Bdir = Bpack + (size_t)dirb * N_ * 16;

  stage_chunk(Bdir, 0, &buf[0][0], w, l);

  const f32x16 zacc = {};
  float racc0[16], racc1[16];
#pragma unroll
  for (int r = 0; r < 16; ++r) { racc0[r] = 3.4e38f; racc1[r] = 3.4e38f; }

  __syncthreads();   // drains vmcnt -> chunk 0 resident

  for (int c = 0; c < NCHUNK; ++c) {
    const int cur = c & 1;
    if (c + 1 < NCHUNK)
      stage_chunk(Bdir, c + 1, &buf[cur ^ 1][0], w, l);   // prefetch

    const unsigned short* bb = &buf[cur][0];
#pragma unroll
    for (int sub = 0; sub < 2; ++sub) {
      const int col = w * 64 + sub * 32 + l31;
      const short8 bfrag = *(const short8*)(bb + (size_t)col * 16 + lhi * 8);
      const f32x16 d0 =
          __builtin_amdgcn_mfma_f32_32x32x16_bf16(afrag0, bfrag, zacc, 0, 0, 0);
      const f32x16 d1 =
          __builtin_amdgcn_mfma_f32_32x32x16_bf16(afrag1, bfrag, zacc, 0, 0, 0);
#pragma unroll
      for (int r = 0; r < 16; ++r) {
        racc0[r] = fminf(racc0[r], d0[r]);   // compiler handles MFMA hazards
        racc1[r] = fminf(racc1[r], d1[r]);
      }
    }
    __syncthreads();   // drains vmcnt (prefetch landed) + releases buf[cur]
  }

  // clamp + butterfly over 32 col-lanes (within each 32-lane half)
#pragma unroll
  for (int r = 0; r < 16; ++r) {
    racc0[r] = fmaxf(racc0[r], 0.0f);
    racc1[r] = fmaxf(racc1[r], 0.0f);
  }
#pragma unroll
  for (int m = 1; m <= 16; m <<= 1) {
#pragma unroll
    for (int r = 0; r < 16; ++r) {
      racc0[r] = fminf(racc0[r], __shfl_xor(racc0[r], m, 64));
      racc1[r] = fminf(racc1[r], __shfl_xor(racc1[r], m, 64));
    }
  }

  // lanes 0 / 32 hold 16-row mins per bank; merge across 8 waves via LDS
  if (l31 == 0) {
#pragma unroll
    for (int r = 0; r < 16; ++r) {
      const int lr = (r & 3) + 8 * (r >> 2) + 4 * lhi;
      atomicMin(&rowlds[lr], __float_as_uint(racc0[r]));
      atomicMin(&rowlds[32 + lr], __float_as_uint(racc1[r]));
    }
  }
  __syncthreads();
  if (tid < 64)
    rowmin[(size_t)dirb * N_ + panel * 64 + tid] = __uint_as_float(rowlds[tid]);
}

// 65536 d2 mins -> sqrt -> sum -> scaled scalar (counter-trick final write).
__global__ __launch_bounds__(256) void chamfer_fin(
    const float* __restrict__ rowmin, float* __restrict__ accws,
    float* __restrict__ out) {
  const int t = blockIdx.x * 256 + threadIdx.x;   // 0..16383
  const float4 v = ((const float4*)rowmin)[t];
  float sum = sqrtf(fmaxf(v.x, 0.f)) + sqrtf(fmaxf(v.y, 0.f)) +
              sqrtf(fmaxf(v.z, 0.f)) + sqrtf(fmaxf(v.w, 0.f));
#pragma unroll
  for (int off = 32; off > 0; off >>= 1) sum += __shfl_down(sum, off, 64);
  __shared__ float ws4[4];
  const int lane = threadIdx.x & 63, wid = threadIdx.x >> 6;
  if (lane == 0) ws4[wid] = sum;
  __syncthreads();
  if (threadIdx.x == 0) {
    const float bs = (ws4[0] + ws4[1]) + (ws4[2] + ws4[3]);
    atomicAdd(&accws[0], bs);
    __threadfence();
    const unsigned old = atomicAdd(((unsigned*)accws) + 1, 1u);
    if (old == gridDim.x - 1) {
      __threadfence();
      const float tot = atomicAdd(&accws[0], 0.0f);
      out[0] = tot * (1.0f / 32768.0f);   // /(B*N) per direction, N==M
    }
  }
}

extern "C" void kernel_launch(void* const* d_in, const int* in_sizes, int n_in,
                              void* d_out, int out_size, void* d_ws, size_t ws_size,
                              hipStream_t stream) {
  const float* pred = (const float*)d_in[0];  // [B, N, 3]
  const float* gt   = (const float*)d_in[1];  // [B, M, 3]
  float* out = (float*)d_out;

  float* accws = (float*)d_ws;                                   // 2 words
  unsigned short* Apack = (unsigned short*)((char*)d_ws + 64);   // 2 MB
  unsigned short* Bpack = Apack + (size_t)2 * B_ * N_ * 16;      // 2 MB
  float* rowmin = (float*)(Bpack + (size_t)2 * B_ * N_ * 16);    // 256 KB

  chamfer_pack<<<256, 256, 0, stream>>>(pred, gt, Apack, Bpack, accws);
  chamfer_mfma<<<dim3(128, 8), THREADS, 0, stream>>>(Apack, Bpack, rowmin);
  chamfer_fin<<<64, 256, 0, stream>>>(rowmin, accws, out);
}